// Round 2
// baseline (865.483 us; speedup 1.0000x reference)
//
#include <hip/hip_runtime.h>
#include <hip/hip_bf16.h>

// NCMOpenMax: probas = softmax(cos(X[n], muK[k]) over k), N=262144, K=512, d=128.
// R1: operand-swapped MFMA (D rows = k, cols = n) so the 4 acc regs of a lane are
// 4 consecutive k columns of out[n][:] -> dwordx4 stores, full 128B lines via L2
// (nontemporal removed). Write-bound target: ~640 MiB total traffic, ~107 us.

using floatx4 = __attribute__((ext_vector_type(4))) float;
using shortx8 = __attribute__((ext_vector_type(8))) short;   // 8 x bf16 (4 VGPRs)

__device__ __forceinline__ short f2bf(float f) {
  unsigned u = __builtin_bit_cast(unsigned, f);
  u += 0x7fffu + ((u >> 16) & 1u);
  return (short)(u >> 16);
}

// ---- Kernel 1: mn[c][k] = muK[c][k] / max(||muK[c]||, eps), bf16, one wave/row.
__global__ void norm_mu_kernel(const float* __restrict__ muK, short* __restrict__ mn) {
  int gid  = blockIdx.x * blockDim.x + threadIdx.x;
  int row  = gid >> 6;
  int lane = gid & 63;
  if (row >= 512) return;
  float2 v = ((const float2*)(muK + row * 128))[lane];
  float ss = v.x * v.x + v.y * v.y;
#pragma unroll
  for (int m = 32; m >= 1; m >>= 1) ss += __shfl_xor(ss, m, 64);
  float inv = rsqrtf(fmaxf(ss, 1e-16f));
  short2 o;
  o.x = f2bf(v.x * inv);
  o.y = f2bf(v.y * inv);
  ((short2*)(mn + row * 128))[lane] = o;
}

// ---- Kernel 2: block = 4 waves = 256 thr. Block owns 64 N-rows; wave w owns
// k-strip [128w, 128w+128). MFMA operands swapped: A = mn tile, B = X tile, so
// D[k_cluster][n] with k consecutive in the reg dimension.
__global__ __launch_bounds__(256, 2)
void cos_softmax_kernel(const float* __restrict__ X,
                        const short* __restrict__ mn,
                        float* __restrict__ out) {
  const int lane = threadIdx.x & 63;
  const int wave = threadIdx.x >> 6;     // 0..3
  const int c15  = lane & 15;
  const int quad = lane >> 4;            // 0..3
  const int nb   = blockIdx.x * 64;      // N-row base for this block
  const int kb   = wave * 128;           // k base for this wave

  floatx4 acc[8][4];                     // [kt][nt]
#pragma unroll
  for (int kt = 0; kt < 8; ++kt)
#pragma unroll
    for (int nt = 0; nt < 4; ++nt)
      acc[kt][nt] = (floatx4){0.f, 0.f, 0.f, 0.f};

  float sumsq[4] = {0.f, 0.f, 0.f, 0.f};

  // d-loop over 128 in 4 steps of 32.
#pragma unroll
  for (int kk = 0; kk < 4; ++kk) {
    // B fragments from X: lane holds X[nb + nt*16 + c15][kk*32 + quad*8 + j]
    shortx8 bfr[4];
#pragma unroll
    for (int nt = 0; nt < 4; ++nt) {
      const float* p = X + (size_t)(nb + nt * 16 + c15) * 128 + kk * 32 + quad * 8;
      float4 u0 = *(const float4*)p;
      float4 u1 = *(const float4*)(p + 4);
      sumsq[nt] += u0.x * u0.x + u0.y * u0.y + u0.z * u0.z + u0.w * u0.w
                 + u1.x * u1.x + u1.y * u1.y + u1.z * u1.z + u1.w * u1.w;
      bfr[nt] = (shortx8){ f2bf(u0.x), f2bf(u0.y), f2bf(u0.z), f2bf(u0.w),
                           f2bf(u1.x), f2bf(u1.y), f2bf(u1.z), f2bf(u1.w) };
    }
    // A fragments from mn: lane holds mn[kb + kt*16 + c15][kk*32 + quad*8 + j]
    shortx8 afr[8];
#pragma unroll
    for (int kt = 0; kt < 8; ++kt) {
      const short* p = mn + (size_t)(kb + kt * 16 + c15) * 128 + kk * 32 + quad * 8;
      afr[kt] = *(const shortx8*)p;
    }
#pragma unroll
    for (int kt = 0; kt < 8; ++kt)
#pragma unroll
      for (int nt = 0; nt < 4; ++nt)
        acc[kt][nt] = __builtin_amdgcn_mfma_f32_16x16x32_bf16(afr[kt], bfr[nt], acc[kt][nt], 0, 0, 0);
  }

  // ||X[n]||^2 per lane's own c15 row (reduce the quad-partials).
  float inv[4];
#pragma unroll
  for (int nt = 0; nt < 4; ++nt) {
    sumsq[nt] += __shfl_xor(sumsq[nt], 16, 64);
    sumsq[nt] += __shfl_xor(sumsq[nt], 32, 64);
    inv[nt] = rsqrtf(fmaxf(sumsq[nt], 1e-16f));
  }

  // exp in place + per-n partial sums over this wave's 128 k values.
  float psum[4] = {0.f, 0.f, 0.f, 0.f};
#pragma unroll
  for (int kt = 0; kt < 8; ++kt)
#pragma unroll
    for (int nt = 0; nt < 4; ++nt)
#pragma unroll
      for (int reg = 0; reg < 4; ++reg) {
        float e = __expf(acc[kt][nt][reg] * inv[nt]);
        acc[kt][nt][reg] = e;
        psum[nt] += e;
      }
  // reduce across quads (k sub-ranges of the same n)
#pragma unroll
  for (int nt = 0; nt < 4; ++nt) {
    psum[nt] += __shfl_xor(psum[nt], 16, 64);
    psum[nt] += __shfl_xor(psum[nt], 32, 64);
  }

  // Cross-wave (cross-k-strip) sum via LDS.
  __shared__ float wsum[4][64];
  __shared__ float tot[64];
  if (quad == 0) {
#pragma unroll
    for (int nt = 0; nt < 4; ++nt)
      wsum[wave][nt * 16 + c15] = psum[nt];
  }
  __syncthreads();
  if (threadIdx.x < 64)
    tot[threadIdx.x] = wsum[0][threadIdx.x] + wsum[1][threadIdx.x]
                     + wsum[2][threadIdx.x] + wsum[3][threadIdx.x];
  __syncthreads();

  float rtot[4];
#pragma unroll
  for (int nt = 0; nt < 4; ++nt)
    rtot[nt] = 1.0f / tot[nt * 16 + c15];

  // Store: lane's 4 regs are 4 consecutive k -> dwordx4. Row n gets contiguous
  // 64B per (kt) instr; adjacent kt fill the same 128B line (L2 merges).
#pragma unroll
  for (int kt = 0; kt < 8; ++kt)
#pragma unroll
    for (int nt = 0; nt < 4; ++nt) {
      float4 o;
      o.x = acc[kt][nt][0] * rtot[nt];
      o.y = acc[kt][nt][1] * rtot[nt];
      o.z = acc[kt][nt][2] * rtot[nt];
      o.w = acc[kt][nt][3] * rtot[nt];
      *(float4*)(out + (size_t)(nb + nt * 16 + c15) * 512 + kb + kt * 16 + quad * 4) = o;
    }
}

extern "C" void kernel_launch(void* const* d_in, const int* in_sizes, int n_in,
                              void* d_out, int out_size, void* d_ws, size_t ws_size,
                              hipStream_t stream) {
  const float* X   = (const float*)d_in[0];   // [262144, 128]
  const float* muK = (const float*)d_in[1];   // [512, 128]
  float* out = (float*)d_out;                 // [262144, 512]
  short* mn  = (short*)d_ws;                  // 512*128 bf16 = 128 KiB scratch

  norm_mu_kernel<<<128, 256, 0, stream>>>(muK, mn);
  cos_softmax_kernel<<<4096, 256, 0, stream>>>(X, mn, out);
}